// Round 10
// baseline (130.120 us; speedup 1.0000x reference)
//
#include <hip/hip_runtime.h>

// Signature_72327249265296: depth-4 path signature, path [64,512,10] fp32.
// out[b] = concat(A1[10], A2[100], A3[1000], A4[10000]).
//
// V9: V2's proven 1-chain-per-thread loop; broadcast d-row moved to the
// VMEM/L1 pipe. Pipe ledger from 9 rounds:
//   - LDS broadcast (V2): 48 LDS-cy/step/wave, hard 41us wall (model-exact).
//   - scalar pipe (V8): s_load + per-step lgkmcnt(0) drains DS too (counted
//     waits unsafe when SMEM+DS mix) -> serialized, 49.7us, VALUBusy 37%.
//   - 5-chain amortization (V4/V5/V7): >=50us all three implementations.
// V9: d-row read per-lane from global dxP (all 64 lanes same address = one
// L1 transaction + broadcast), counted on vmcnt -- SEPARATE from ds_read's
// lgkmcnt -- so the compiler pipelines loads across unrolled steps with its
// own counted vmcnt waits. Address forced into a VGPR via opaque v_mov asm
// so uniformity analysis cannot scalarize back to s_load (V3's suspected
// failure). Segment rows = 3KB -> L1-resident.
// Geometry: NSEG=8 x SEGLEN=64, 2048 blocks = 32 waves/CU (8/SIMD at ~48
// VGPR). Budget: VALU 10.2us/SIMD, LDS 7.7us/CU, VMEM ~2.6us -> ~13us.
// Chen per-step recurrence (validated V1-V8):
//   p1 = A1/6 + dxi/24 ; q1 = A1/2 + dxi/6 ; r1 = A1 + dxi/2
//   p2 = A2/2 + p1*dxj ; q2 = A2 + q1*dxj  ; A2 += r1*dxj
//   p3 = A3 + p2*dxk   ; A3 += q2*dxk      ; A1 += dxi ; A4[l] += p3*d[l]
// Segment combine: serial Chen fold of NSEG=8 partials (validated V2-V8).
// The ~44us 256MiB workspace poison is in the timed graph unconditionally
// (present in round 0 which used no workspace) -> workspace use is free.

#define CH      10
#define NSTEPS  511
#define SIGSZ   11110
#define WSSEG   11112                    // per-partial stride (16B-aligned)
#define NSEG    8
#define SEGLEN  64
#define TRP     68                       // transposed LDS stride

#define DXP_OFF (64 * NSEG * WSSEG)      // float offset of dxP in workspace

__global__ __launch_bounds__(256)
void sig_prep(const float* __restrict__ path, float* __restrict__ dxP) {
    const int nElem = 64 * 512 * 12;     // [64][512][12] padded rows
    for (int e = blockIdx.x * 256 + threadIdx.x; e < nElem;
         e += gridDim.x * 256) {
        const int row = e / 12;
        const int c   = e - row * 12;
        const int b   = row >> 9;
        const int s   = row & 511;
        float v = 0.f;
        if (s < NSTEPS && c < CH) {
            const float* pp = path + ((size_t)b * 512 + s) * CH + c;
            v = pp[CH] - pp[0];
        }
        dxP[e] = v;
    }
}

// one step: broadcast row DR read from GLOBAL (L1-resident, vmcnt pipe)
#define STEP(DXI, DXJ, DXK, DR) do {                                   \
    const float4 d0 = *(const float4*)(DR);                            \
    const float4 d1 = *(const float4*)((DR) + 4);                      \
    const float2 d2 = *(const float2*)((DR) + 8);                      \
    const float dxi = (DXI), dxj = (DXJ), dxk = (DXK);                 \
    const float p1 = a1 * (1.f / 6.f) + dxi * (1.f / 24.f);            \
    const float q1 = a1 * 0.5f        + dxi * (1.f / 6.f);             \
    const float r1 = a1               + dxi * 0.5f;                    \
    const float p2 = a2 * 0.5f + p1 * dxj;                             \
    const float q2 = a2        + q1 * dxj;                             \
    a2 += r1 * dxj;                                                    \
    const float p3 = a3 + p2 * dxk;                                    \
    a3 += q2 * dxk;                                                    \
    a1 += dxi;                                                         \
    a4[0] += p3 * d0.x; a4[1] += p3 * d0.y;                            \
    a4[2] += p3 * d0.z; a4[3] += p3 * d0.w;                            \
    a4[4] += p3 * d1.x; a4[5] += p3 * d1.y;                            \
    a4[6] += p3 * d1.z; a4[7] += p3 * d1.w;                            \
    a4[8] += p3 * d2.x; a4[9] += p3 * d2.y;                            \
} while (0)

__global__ __launch_bounds__(256)
void sig_partial(const float* __restrict__ path, const float* __restrict__ dxP,
                 float* __restrict__ ws) {
    __shared__ __align__(16) float trL[CH * TRP];   // [c][s] transposed dx

    const int tid  = threadIdx.x;
    const int bx   = blockIdx.x;          // 2048 = 64 batches x 8 seg x 4 parts
    const int b    = bx >> 5;
    const int seg  = (bx >> 2) & 7;
    const int part = bx & 3;
    const int s0   = seg * SEGLEN;

    // ---- stage transposed per-lane dx into LDS (from path, V2-proven) ----
    const float* p = path + (size_t)b * (512 * CH) + s0 * CH;
    for (int e = tid; e < SEGLEN * CH; e += 256) {
        const int s = e / CH;
        const int c = e - s * CH;
        float v = 0.f;
        if (s0 + s < NSTEPS) v = p[e + CH] - p[e];   // seg 7 step 63 = 0 pad
        trL[c * TRP + s] = v;
    }
    __syncthreads();

    const int id = part * 256 + tid;      // chain id = i*100 + j*10 + k
    if (id < 1000) {
        const int ci = id / 100;
        const int cj = (id / 10) % 10;
        const int ck = id % 10;

        float a1 = 0.f, a2 = 0.f, a3 = 0.f;
        float a4[10];
        #pragma unroll
        for (int l = 0; l < 10; ++l) a4[l] = 0.f;

        const float* ti = trL + ci * TRP;
        const float* tj = trL + cj * TRP;
        const float* tk = trL + ck * TRP;

        // wave-uniform row base -- but force the offset through a VGPR so
        // uniformity analysis CANNOT scalarize these loads to s_load
        // (keeps them on the vmcnt pipe, pipelinable against ds_reads).
        int voff;
        asm("v_mov_b32 %0, 0" : "=v"(voff));
        const float* dp = dxP + (size_t)(b * 512 + s0) * 12 + voff;

        #pragma unroll 2
        for (int s4 = 0; s4 < SEGLEN; s4 += 4) {
            const float4 vi = *(const float4*)(ti + s4);
            const float4 vj = *(const float4*)(tj + s4);
            const float4 vk = *(const float4*)(tk + s4);
            const float* dr = dp + s4 * 12;
            STEP(vi.x, vj.x, vk.x, dr);
            STEP(vi.y, vj.y, vk.y, dr + 12);
            STEP(vi.z, vj.z, vk.z, dr + 24);
            STEP(vi.w, vj.w, vk.w, dr + 36);
        }

        // ---- epilogue: write this chain's share of the segment partial ----
        float* ob = ws + (size_t)(b * NSEG + seg) * WSSEG;
        float* o4 = ob + 1110 + id * 10;
        #pragma unroll
        for (int l = 0; l < 10; ++l) o4[l] = a4[l];
        ob[110 + id] = a3;
        if (ck == 0)            ob[10 + ci * 10 + cj] = a2;
        if (ck == 0 && cj == 0) ob[ci] = a1;
    }
}

__global__ __launch_bounds__(256)
void sig_combine(const float* __restrict__ ws, float* __restrict__ out) {
    __shared__ float B[1110];             // levels 1-3 of one segment partial

    const int tid  = threadIdx.x;
    const int b    = blockIdx.x >> 2;
    const int part = blockIdx.x & 3;
    const int id   = part * 256 + tid;
    const bool valid = (id < 1000);

    const int ci = id / 100;
    const int cj = (id / 10) % 10;
    const int ck = id % 10;

    const float* w0 = ws + (size_t)b * NSEG * WSSEG;

    float a1 = 0.f, a2 = 0.f, a3 = 0.f;
    float a4[10];
    #pragma unroll
    for (int l = 0; l < 10; ++l) a4[l] = 0.f;
    if (valid) {
        a1 = w0[ci];
        a2 = w0[10 + ci * 10 + cj];
        a3 = w0[110 + id];
        #pragma unroll
        for (int l = 0; l < 10; ++l) a4[l] = w0[1110 + id * 10 + l];
    }

    for (int s = 1; s < NSEG; ++s) {
        const float* wb = w0 + (size_t)s * WSSEG;
        __syncthreads();                  // previous iter done reading B
        for (int e = tid; e < 1110; e += 256) B[e] = wb[e];
        __syncthreads();

        if (valid) {
            const float b1i   = B[ci];
            const float b1j   = B[cj];
            const float b1k   = B[ck];
            const float b2_ij = B[10 + ci * 10 + cj];
            const float b2_jk = B[10 + cj * 10 + ck];
            const float b3ijk = B[110 + id];

            float b4v[10];
            #pragma unroll
            for (int l = 0; l < 10; ++l) b4v[l] = wb[1110 + id * 10 + l];

            // Z4 uses OLD a1,a2,a3 (computed before lower levels update)
            #pragma unroll
            for (int l = 0; l < 10; ++l)
                a4[l] += a3 * B[l] + a2 * B[10 + ck * 10 + l]
                       + a1 * B[110 + (cj * 10 + ck) * 10 + l] + b4v[l];
            a3 += a2 * b1k + a1 * b2_jk + b3ijk;
            a2 += a1 * b1j + b2_ij;
            a1 += b1i;
        }
    }

    if (valid) {
        float* ob = out + (size_t)b * SIGSZ;
        float* o4 = ob + 1110 + id * 10;
        #pragma unroll
        for (int l = 0; l < 10; ++l) o4[l] = a4[l];
        ob[110 + id] = a3;
        if (ck == 0)            ob[10 + ci * 10 + cj] = a2;
        if (ck == 0 && cj == 0) ob[ci] = a1;
    }
}

extern "C" void kernel_launch(void* const* d_in, const int* in_sizes, int n_in,
                              void* d_out, int out_size, void* d_ws, size_t ws_size,
                              hipStream_t stream) {
    const float* path = (const float*)d_in[0];   // [64, 512, 10] fp32
    float* out = (float*)d_out;                  // [64, 11110] fp32
    float* ws  = (float*)d_ws;                   // ~24.3 MB used

    float* parts = ws;
    float* dxP   = ws + DXP_OFF;

    sig_prep   <<<dim3(512),  dim3(256), 0, stream>>>(path, dxP);
    sig_partial<<<dim3(2048), dim3(256), 0, stream>>>(path, dxP, parts);
    sig_combine<<<dim3(256),  dim3(256), 0, stream>>>(parts, out);
}

// Round 11
// 97.022 us; speedup vs baseline: 1.3411x; 1.3411x over previous
//
#include <hip/hip_runtime.h>

// Signature_72327249265296: depth-4 path signature, path [64,512,10] fp32.
// out[b] = concat(A1[10], A2[100], A3[1000], A4[10000]).
//
// V10: 2 chains per thread, V2's exact loop shape. Pipe ledger (10 rounds):
// the broadcast d-row costs full 64-lane return bandwidth on EVERY pipe
// (LDS 41us / SMEM 50 / VMEM 59 / readlane 55) -- it cannot be made cheaper,
// only read FEWER times. Row traffic = 2.5KB x wave-steps:
//   - V2 (1 chain/thr): 524k wave-steps, 41us, EXACTLY matches LDS model.
//   - 5-chain (V4/V5/V7): 131k wave-steps but ~110 VGPR -> loses load
//     pipelining (~250cy/wave-step, NOT scratch: capped == uncapped).
//   - V10 (2-chain): 262k wave-steps at ~35 live floats (~60 VGPR), still
//     in V2's proven small-state pipelining regime. Thread owns (i,j,k) and
//     (i,j,k+5); shared Horner prefix on (i,j); one extra b32 indexed read.
// Model: LDS 3.5KB/step/wave -> 17.6us floor x1.24 (V2 factor) ~ 22us;
// VALU 32 inst/step -> 6.8us; 1024 blocks = 16 waves/CU (4/SIMD).
// Chen per-step recurrence (validated V1-V9):
//   p1 = A1/6 + dxi/24 ; q1 = A1/2 + dxi/6 ; r1 = A1 + dxi/2
//   p2 = A2/2 + p1*dxj ; q2 = A2 + q1*dxj  ; A2 += r1*dxj
//   per chain c in {k, k+5}: p3 = A3c + p2*dxc ; A3c += q2*dxc ;
//                            A4c[l] += p3*d[l]
//   A1 += dxi
// Segment combine: serial Chen fold of NSEG=8 partials (validated V2-V9).
// The ~44us 256MiB workspace poison is in the timed graph unconditionally
// (present in round 0 which used no workspace) -> workspace use is free.

#define CH      10
#define NSTEPS  511
#define SIGSZ   11110
#define WSSEG   11112                    // per-partial stride (16B-aligned)
#define NSEG    8
#define SEGLEN  64
#define TRP     68                       // transposed LDS stride

__global__ __launch_bounds__(256)
void sig_partial(const float* __restrict__ path, float* __restrict__ ws) {
    __shared__ __align__(16) float rowL[SEGLEN * 12];   // [s][c] padded rows
    __shared__ __align__(16) float trL[CH * TRP];       // [c][s] transposed

    const int tid  = threadIdx.x;
    const int bx   = blockIdx.x;          // 1024 = 64 batches x 8 seg x 2 parts
    const int b    = bx >> 4;
    const int seg  = (bx >> 1) & 7;
    const int part = bx & 1;
    const int s0   = seg * SEGLEN;

    // ---- stage this segment's increments into both LDS layouts ----
    const float* p = path + (size_t)b * (512 * CH) + s0 * CH;
    for (int e = tid; e < SEGLEN * CH; e += 256) {
        const int s = e / CH;
        const int c = e - s * CH;
        float v = 0.f;
        if (s0 + s < NSTEPS) v = p[e + CH] - p[e];   // seg 7 step 63 = 0 pad
        rowL[s * 12 + c] = v;
        trL[c * TRP + s] = v;
    }
    __syncthreads();

    // chain-pair id: 500 per batch-segment (k in 0..4 paired with k+5)
    const int cp = part * 256 + tid;
    if (cp < 500) {
        const int ci  = cp / 50;
        const int rem = cp - ci * 50;
        const int cj  = rem / 5;
        const int ck  = rem - cj * 5;     // 0..4 ; partner is ck+5

        float a1 = 0.f, a2 = 0.f, a3a = 0.f, a3b = 0.f;
        float a4a[10], a4b[10];
        #pragma unroll
        for (int l = 0; l < 10; ++l) { a4a[l] = 0.f; a4b[l] = 0.f; }

        const float* ti  = trL + ci * TRP;
        const float* tj  = trL + cj * TRP;
        const float* tk  = trL + ck * TRP;
        const float* tk2 = trL + (ck + 5) * TRP;

        #pragma unroll 4
        for (int s = 0; s < SEGLEN; ++s) {
            const float* row = rowL + s * 12;
            // broadcast row (d-values for the A4 updates)
            const float4 d0 = *(const float4*)(row);
            const float4 d1 = *(const float4*)(row + 4);
            const float2 d2 = *(const float2*)(row + 8);
            // lane-indexed reads (V2-style b32, <=2-way bank alias)
            const float dxi  = ti[s];
            const float dxj  = tj[s];
            const float dxk  = tk[s];
            const float dxk2 = tk2[s];

            // shared (i,j) Horner prefix
            const float p1 = a1 * (1.f / 6.f) + dxi * (1.f / 24.f);
            const float q1 = a1 * 0.5f        + dxi * (1.f / 6.f);
            const float r1 = a1               + dxi * 0.5f;
            const float p2 = a2 * 0.5f + p1 * dxj;
            const float q2 = a2        + q1 * dxj;
            a2 += r1 * dxj;
            a1 += dxi;

            // chain A: (i,j,ck)
            const float p3a = a3a + p2 * dxk;
            a3a += q2 * dxk;
            // chain B: (i,j,ck+5)
            const float p3b = a3b + p2 * dxk2;
            a3b += q2 * dxk2;

            a4a[0] += p3a * d0.x; a4b[0] += p3b * d0.x;
            a4a[1] += p3a * d0.y; a4b[1] += p3b * d0.y;
            a4a[2] += p3a * d0.z; a4b[2] += p3b * d0.z;
            a4a[3] += p3a * d0.w; a4b[3] += p3b * d0.w;
            a4a[4] += p3a * d1.x; a4b[4] += p3b * d1.x;
            a4a[5] += p3a * d1.y; a4b[5] += p3b * d1.y;
            a4a[6] += p3a * d1.z; a4b[6] += p3b * d1.z;
            a4a[7] += p3a * d1.w; a4b[7] += p3b * d1.w;
            a4a[8] += p3a * d2.x; a4b[8] += p3b * d2.x;
            a4a[9] += p3a * d2.y; a4b[9] += p3b * d2.y;
        }

        // ---- epilogue: write both chains' share of the segment partial ----
        const int ida = ci * 100 + cj * 10 + ck;   // and ida+5 for chain B
        float* ob = ws + (size_t)(b * NSEG + seg) * WSSEG;
        float* o4a = ob + 1110 + ida * 10;
        float* o4b = o4a + 50;                     // (ida+5)*10
        #pragma unroll
        for (int l = 0; l < 10; ++l) { o4a[l] = a4a[l]; o4b[l] = a4b[l]; }
        ob[110 + ida]     = a3a;
        ob[110 + ida + 5] = a3b;
        if (ck == 0)            ob[10 + ci * 10 + cj] = a2;
        if (ck == 0 && cj == 0) ob[ci] = a1;
    }
}

__global__ __launch_bounds__(256)
void sig_combine(const float* __restrict__ ws, float* __restrict__ out) {
    __shared__ float B[1110];             // levels 1-3 of one segment partial

    const int tid  = threadIdx.x;
    const int b    = blockIdx.x >> 2;
    const int part = blockIdx.x & 3;
    const int id   = part * 256 + tid;
    const bool valid = (id < 1000);

    const int ci = id / 100;
    const int cj = (id / 10) % 10;
    const int ck = id % 10;

    const float* w0 = ws + (size_t)b * NSEG * WSSEG;

    float a1 = 0.f, a2 = 0.f, a3 = 0.f;
    float a4[10];
    #pragma unroll
    for (int l = 0; l < 10; ++l) a4[l] = 0.f;
    if (valid) {
        a1 = w0[ci];
        a2 = w0[10 + ci * 10 + cj];
        a3 = w0[110 + id];
        #pragma unroll
        for (int l = 0; l < 10; ++l) a4[l] = w0[1110 + id * 10 + l];
    }

    for (int s = 1; s < NSEG; ++s) {
        const float* wb = w0 + (size_t)s * WSSEG;
        __syncthreads();                  // previous iter done reading B
        for (int e = tid; e < 1110; e += 256) B[e] = wb[e];
        __syncthreads();

        if (valid) {
            const float b1i   = B[ci];
            const float b1j   = B[cj];
            const float b1k   = B[ck];
            const float b2_ij = B[10 + ci * 10 + cj];
            const float b2_jk = B[10 + cj * 10 + ck];
            const float b3ijk = B[110 + id];

            float b4v[10];
            #pragma unroll
            for (int l = 0; l < 10; ++l) b4v[l] = wb[1110 + id * 10 + l];

            // Z4 uses OLD a1,a2,a3 (computed before lower levels update)
            #pragma unroll
            for (int l = 0; l < 10; ++l)
                a4[l] += a3 * B[l] + a2 * B[10 + ck * 10 + l]
                       + a1 * B[110 + (cj * 10 + ck) * 10 + l] + b4v[l];
            a3 += a2 * b1k + a1 * b2_jk + b3ijk;
            a2 += a1 * b1j + b2_ij;
            a1 += b1i;
        }
    }

    if (valid) {
        float* ob = out + (size_t)b * SIGSZ;
        float* o4 = ob + 1110 + id * 10;
        #pragma unroll
        for (int l = 0; l < 10; ++l) o4[l] = a4[l];
        ob[110 + id] = a3;
        if (ck == 0)            ob[10 + ci * 10 + cj] = a2;
        if (ck == 0 && cj == 0) ob[ci] = a1;
    }
}

extern "C" void kernel_launch(void* const* d_in, const int* in_sizes, int n_in,
                              void* d_out, int out_size, void* d_ws, size_t ws_size,
                              hipStream_t stream) {
    const float* path = (const float*)d_in[0];   // [64, 512, 10] fp32
    float* out = (float*)d_out;                  // [64, 11110] fp32
    float* ws  = (float*)d_ws;                   // 64*8*11112 floats = 22.8 MB

    sig_partial<<<dim3(1024), dim3(256), 0, stream>>>(path, ws);
    sig_combine<<<dim3(256),  dim3(256), 0, stream>>>(ws, out);
}